// Round 6
// baseline (153.991 us; speedup 1.0000x reference)
//
#include <hip/hip_runtime.h>
#include <stdint.h>

#define SEQ 64
#define D 28
#define EMB 784   // 28*28
#define NW 4      // waves per block (one block = one sentence)
#define CH 16     // words per wave: two interleaved 8-word chains
#define BUFF 832  // B-buffer floats: 3328 B = exact DMA coverage (3*1024+256)
#define SCRW 36   // scratch row stride (floats); 2-way-free banks

typedef float float4v __attribute__((ext_vector_type(4)));
typedef __bf16 bf16x8 __attribute__((ext_vector_type(8)));

union FragU { unsigned u[4]; bf16x8 v; };

__device__ __forceinline__ unsigned fbits(float x) { union { float f; unsigned u; } t; t.f = x; return t.u; }
__device__ __forceinline__ float fof(unsigned u) { union { unsigned u; float f; } t; t.u = u; return t.f; }

// Truncation hi/lo split of 4 fp32 into packed bf16 pairs (x0 in low half).
// EXACTLY the arithmetic of the harness-verified R5 split.
struct HL4 { unsigned h01, h23, l01, l23; };
__device__ __forceinline__ HL4 hilo4(float x0, float x1, float x2, float x3) {
    unsigned u0 = fbits(x0), u1 = fbits(x1), u2 = fbits(x2), u3 = fbits(x3);
    HL4 r;
    r.h01 = (u0 >> 16) | (u1 & 0xFFFF0000u);
    r.h23 = (u2 >> 16) | (u3 & 0xFFFF0000u);
    unsigned l0 = fbits(x0 - fof(u0 & 0xFFFF0000u));
    unsigned l1 = fbits(x1 - fof(u1 & 0xFFFF0000u));
    unsigned l2 = fbits(x2 - fof(u2 & 0xFFFF0000u));
    unsigned l3 = fbits(x3 - fof(u3 & 0xFFFF0000u));
    r.l01 = (l0 >> 16) | (l1 & 0xFFFF0000u);
    r.l23 = (l2 >> 16) | (l3 & 0xFFFF0000u);
    return r;
}

// ---- async global->LDS DMA of one 3136 B row (+192 B tail overread, stays
// within allocation slack; lands in LDS bytes [3136,3328), never read).
__device__ __forceinline__ void dma_row(const float* grow, float* lbuf, int lane)
{
    const char* g16 = (const char*)grow + lane * 16;
    const char* g4  = (const char*)grow + 3072 + lane * 4;
    char* l = (char*)lbuf;
    __builtin_amdgcn_global_load_lds((const __attribute__((address_space(1))) void*)(g16),
                                     (__attribute__((address_space(3))) void*)(l), 16, 0, 0);
    __builtin_amdgcn_global_load_lds((const __attribute__((address_space(1))) void*)(g16 + 1024),
                                     (__attribute__((address_space(3))) void*)(l + 1024), 16, 0, 0);
    __builtin_amdgcn_global_load_lds((const __attribute__((address_space(1))) void*)(g16 + 2048),
                                     (__attribute__((address_space(3))) void*)(l + 2048), 16, 0, 0);
    __builtin_amdgcn_global_load_lds((const __attribute__((address_space(1))) void*)(g4),
                                     (__attribute__((address_space(3))) void*)(l + 3072), 4, 0, 0);
}

// ================= transpose-space step (two-term MFMA packing) ===========
// acc <- mat^T * acc; layouts and k-slot packing exactly as verified in R5:
//   slot t=0..3: logical k=16KB+4q+t as HI; slot t=4..7: same k (A=lo, B=hi/0)
//   MFMA1: A={Ah|Al}, B={Bh|Bh};  MFMA2: A={Ah|Al}, B={Bl|0}   (16 MFMA/step)
// B operand from acc fully IN-LANE. Logical k=28..31 zeroed on A (q3,KB=1).
template<int STRIDE>
__device__ __forceinline__ void stepT(const float* a0, const float* a1,
                                      float4v acc[2][2], bool q3)
{
    float av[2][2][4];
#pragma unroll
    for (int t = 0; t < 4; ++t)
#pragma unroll
        for (int Ro = 0; Ro < 2; ++Ro) {
            av[Ro][0][t] = a0[t * STRIDE + 16 * Ro];
            av[Ro][1][t] = a1[t * STRIDE + 16 * Ro];
        }
#pragma unroll
    for (int Ro = 0; Ro < 2; ++Ro)
#pragma unroll
        for (int t = 0; t < 4; ++t)
            av[Ro][1][t] = q3 ? 0.f : av[Ro][1][t];   // logical k=28..31 -> 0

    FragU Af[2][2];
#pragma unroll
    for (int Ro = 0; Ro < 2; ++Ro)
#pragma unroll
        for (int KB = 0; KB < 2; ++KB) {
            HL4 h = hilo4(av[Ro][KB][0], av[Ro][KB][1], av[Ro][KB][2], av[Ro][KB][3]);
            Af[Ro][KB].u[0] = h.h01; Af[Ro][KB].u[1] = h.h23;
            Af[Ro][KB].u[2] = h.l01; Af[Ro][KB].u[3] = h.l23;
        }

    FragU Bd[2][2], B2[2][2];
#pragma unroll
    for (int KB = 0; KB < 2; ++KB)
#pragma unroll
        for (int Co = 0; Co < 2; ++Co) {
            HL4 h = hilo4(acc[KB][Co][0], acc[KB][Co][1], acc[KB][Co][2], acc[KB][Co][3]);
            Bd[KB][Co].u[0] = h.h01; Bd[KB][Co].u[1] = h.h23;
            Bd[KB][Co].u[2] = h.h01; Bd[KB][Co].u[3] = h.h23;
            B2[KB][Co].u[0] = h.l01; B2[KB][Co].u[1] = h.l23;
            B2[KB][Co].u[2] = 0u;    B2[KB][Co].u[3] = 0u;
        }

#pragma unroll
    for (int Ro = 0; Ro < 2; ++Ro)
#pragma unroll
        for (int Co = 0; Co < 2; ++Co) {
            float4v d = {0.f, 0.f, 0.f, 0.f};
#pragma unroll
            for (int KB = 0; KB < 2; ++KB) {
                d = __builtin_amdgcn_mfma_f32_16x16x32_bf16(Af[Ro][KB].v, Bd[KB][Co].v, d, 0, 0, 0);
                d = __builtin_amdgcn_mfma_f32_16x16x32_bf16(Af[Ro][KB].v, B2[KB][Co].v, d, 0, 0, 0);
            }
            acc[Ro][Co] = d;
        }
}

// ================= fused kernel: one block per sentence =================
// 4 waves; wave w runs TWO interleaved 8-word chains (a = words 0..7,
// b = words 8..15 of its 16): sub-step order a0,b0,a1,b1,... Consecutive
// sub-steps hit different accumulators -> the acc->split->MFMA dependence
// spans 2 sub-steps (2x slack vs R5's single chain). DMA schedule, buffer
// rotation (row s -> buf s%3, depth-2 prefetch, vmcnt(8)) identical to R5.
// Merge: T_w = T_b * T_a via one publish(P_b) + stepT. Then block combine.
// LDS: 4 waves x 3 x 3328 B = 39936 B -> 4 blocks/CU: whole grid resident.
__global__ __launch_bounds__(NW * 64, 4) void w2m_fusedT3i(
    const int* __restrict__ sent,
    const float* __restrict__ table,
    float* __restrict__ out)
{
    __shared__ float SH[NW * 3 * BUFF] __attribute__((aligned(16)));
    const int lane = threadIdx.x & 63;
    const int wid  = threadIdx.x >> 6;   // 0..3
    const int b = blockIdx.x;
    const int c = lane & 15;
    const int quad = lane >> 4;
    const bool q3 = (quad == 3);
    const int qc = q3 ? 2 : quad;        // clamp so chain a1 reads stay <832

    float* B0  = &SH[wid * 3 * BUFF];
    float* B1  = B0 + BUFF;
    float* B2b = B0 + 2 * BUFF;

    const int myidx = sent[b * SEQ + CH * wid + (lane & 15)];
    // row sequence s: a0,b0,a1,b1,... -> local word (s&1)*8 + (s>>1)
    int jr[16];
#pragma unroll
    for (int s = 0; s < 16; ++s)
        jr[s] = __builtin_amdgcn_readlane(myidx, (s & 1) * 8 + (s >> 1));

    // ---- prologue: rows 0,1,2 in flight (bufs 0,1,2)
    dma_row(table + (size_t)jr[0] * EMB, B0, lane);
    dma_row(table + (size_t)jr[1] * EMB, B1, lane);
    dma_row(table + (size_t)jr[2] * EMB, B2b, lane);
    __builtin_amdgcn_s_waitcnt(0x0078);  // vmcnt(8): row0 landed

    // init accA = (word a0)^T (transposed b128 read; pad cols junk, masked
    // at store; pad rows get A-side zeros every step).
    float4v accA[2][2], accB[2][2];
#pragma unroll
    for (int R = 0; R < 2; ++R)
#pragma unroll
        for (int Cc = 0; Cc < 2; ++Cc) {
            int rcl = 16 * Cc + c; if (rcl > 27) rcl = 27;
            accA[R][Cc] = *(const float4v*)&B0[rcl * D + 16 * R + 4 * quad];
        }

    // per-lane, per-buffer A bases (all step offsets become immediates)
    const float* a00 = B0  + 4 * quad * D + c;
    const float* a10 = B0  + (16 + 4 * qc) * D + c;
    const float* a01 = B1  + 4 * quad * D + c;
    const float* a11 = B1  + (16 + 4 * qc) * D + c;
    const float* a02 = B2b + 4 * quad * D + c;
    const float* a12 = B2b + (16 + 4 * qc) * D + c;

    // ---- interleaved chains, fully unrolled. Per sub-step s:
    // (a) lgkmcnt(0): prior sub-step's reads of buf (s+2)%3 are done;
    // (b) issue row s+2 into buf (s+2)%3 (tail re-issues row 15, dup-safe);
    // (c) vmcnt(8): row s landed, rows s+1, s+2 stay in flight.
    // s==1 inits accB; s>=2 steps acc (s even -> accA, odd -> accB).
#pragma unroll
    for (int s = 1; s < 16; ++s) {
        __builtin_amdgcn_s_waitcnt(0xC07F);  // lgkmcnt(0)
        const int sn = (s + 2 < 16) ? s + 2 : 15;
        const int tb = (s + 2) % 3;
        float* nB = (tb == 0) ? B0 : (tb == 1) ? B1 : B2b;
        dma_row(table + (size_t)jr[sn] * EMB, nB, lane);

        __builtin_amdgcn_sched_barrier(0);
        __builtin_amdgcn_s_waitcnt(0x0078);  // vmcnt(8) lgkmcnt(0)
        __builtin_amdgcn_sched_barrier(0);

        if (s == 1) {
            // init accB = (word b0)^T from buf1
#pragma unroll
            for (int R = 0; R < 2; ++R)
#pragma unroll
                for (int Cc = 0; Cc < 2; ++Cc) {
                    int rcl = 16 * Cc + c; if (rcl > 27) rcl = 27;
                    accB[R][Cc] = *(const float4v*)&B1[rcl * D + 16 * R + 4 * quad];
                }
        } else {
            float4v (*acc)[2] = (s & 1) ? accB : accA;
            const int cb = s % 3;
            if (cb == 0)      stepT<D>(a00, a10, acc, q3);
            else if (cb == 1) stepT<D>(a01, a11, acc, q3);
            else              stepT<D>(a02, a12, acc, q3);
        }
    }

    // ---- merge: T_w = T_b * T_a. Publish P_b = T_b^T into own scratch
    // (transposed write, 8-way bank aliasing, once per wave), then one stepT
    // with acc = accA: acc <- (P_b)^T * acc = T_b * T_a.
    __builtin_amdgcn_s_waitcnt(0x0070);  // vmcnt(0) lgkmcnt(0): drain dups
    __builtin_amdgcn_sched_barrier(0);
    float* SCR = B0;  // region 3*832 = 2496 floats; max idx used 1147
#pragma unroll
    for (int KB = 0; KB < 2; ++KB)
#pragma unroll
        for (int Co = 0; Co < 2; ++Co)
#pragma unroll
            for (int i = 0; i < 4; ++i)
                SCR[(16 * Co + c) * SCRW + 16 * KB + 4 * quad + i] = accB[KB][Co][i];
    __builtin_amdgcn_sched_barrier(0);
    __builtin_amdgcn_s_waitcnt(0xC07F);  // lgkmcnt(0): publish visible
    __builtin_amdgcn_sched_barrier(0);
    stepT<SCRW>(SCR + 4 * quad * SCRW + c,
                SCR + (16 + 4 * quad) * SCRW + c, accA, q3);

    // ---- publish T_w row-major (WAR on SCR: drain stepT's reads first)
    __builtin_amdgcn_s_waitcnt(0xC07F);  // lgkmcnt(0)
    __builtin_amdgcn_sched_barrier(0);
#pragma unroll
    for (int R = 0; R < 2; ++R)
#pragma unroll
        for (int Cc = 0; Cc < 2; ++Cc)
#pragma unroll
            for (int i = 0; i < 4; ++i)
                SCR[(16 * R + 4 * quad + i) * SCRW + 16 * Cc + c] = accA[R][Cc][i];
    __syncthreads();

    // ---- combine (redundant on all waves): X = P3, then X = Pj*X, j=2,1,0.
    const float* S3 = &SH[3 * 3 * BUFF];
#pragma unroll
    for (int R = 0; R < 2; ++R)
#pragma unroll
        for (int Cc = 0; Cc < 2; ++Cc)
            accA[R][Cc] = *(const float4v*)&S3[(16 * Cc + c) * SCRW + 16 * R + 4 * quad];

#pragma unroll
    for (int j = 2; j >= 0; --j) {
        const float* reg = &SH[j * 3 * BUFF];
        stepT<SCRW>(reg + 4 * quad * SCRW + c,
                    reg + (16 + 4 * quad) * SCRW + c, accA, q3);
    }

    // ---- store rows/cols < 28
    if (wid == 0) {
        float* orow = out + (size_t)b * EMB;
#pragma unroll
        for (int R = 0; R < 2; ++R)
#pragma unroll
            for (int Cc = 0; Cc < 2; ++Cc)
#pragma unroll
                for (int i = 0; i < 4; ++i) {
                    const int row = 16 * R + 4 * quad + i;
                    const int col = 16 * Cc + c;
                    if (row < D && col < D) orow[row * D + col] = accA[R][Cc][i];
                }
    }
}

extern "C" void kernel_launch(void* const* d_in, const int* in_sizes, int n_in,
                              void* d_out, int out_size, void* d_ws, size_t ws_size,
                              hipStream_t stream) {
    const int* sent = (const int*)d_in[0];
    const float* table = (const float*)d_in[1];
    float* out = (float*)d_out;
    const int batch = in_sizes[0] / SEQ;                  // 1024
    (void)d_ws; (void)ws_size;                            // workspace unused

    hipLaunchKernelGGL(w2m_fusedT3i, dim3(batch), dim3(NW * 64), 0, stream,
                       sent, table, out);
}

// Round 8
// 149.350 us; speedup vs baseline: 1.0311x; 1.0311x over previous
//
#include <hip/hip_runtime.h>
#include <stdint.h>

#define SEQ 64
#define D 28
#define EMB 784   // 28*28
#define NW 4      // waves per block (one block = one sentence)
#define CH 16     // words per wave: two interleaved 8-word chains
#define BUFF 832  // B-buffer floats: 3328 B DMA region (3*1024 + tail)
#define SCRW 36   // scratch row stride (floats); 2-way-free banks

typedef float float4v __attribute__((ext_vector_type(4)));
typedef __bf16 bf16x8 __attribute__((ext_vector_type(8)));
typedef _Float16 half8 __attribute__((ext_vector_type(8)));

union FragU { unsigned u[4]; bf16x8 v; };

__device__ __forceinline__ unsigned fbits(float x) { union { float f; unsigned u; } t; t.f = x; return t.u; }
__device__ __forceinline__ float fof(unsigned u) { union { unsigned u; float f; } t; t.u = u; return t.f; }

// Truncation hi/lo split (harness-verified R5/R6 arithmetic) — used only in
// the merge/combine stepT path now.
struct HL4 { unsigned h01, h23, l01, l23; };
__device__ __forceinline__ HL4 hilo4(float x0, float x1, float x2, float x3) {
    unsigned u0 = fbits(x0), u1 = fbits(x1), u2 = fbits(x2), u3 = fbits(x3);
    HL4 r;
    r.h01 = (u0 >> 16) | (u1 & 0xFFFF0000u);
    r.h23 = (u2 >> 16) | (u3 & 0xFFFF0000u);
    unsigned l0 = fbits(x0 - fof(u0 & 0xFFFF0000u));
    unsigned l1 = fbits(x1 - fof(u1 & 0xFFFF0000u));
    unsigned l2 = fbits(x2 - fof(u2 & 0xFFFF0000u));
    unsigned l3 = fbits(x3 - fof(u3 & 0xFFFF0000u));
    r.l01 = (l0 >> 16) | (l1 & 0xFFFF0000u);
    r.l23 = (l2 >> 16) | (l3 & 0xFFFF0000u);
    return r;
}

// ---- async global->LDS DMA of one 3136 B row. Main loads: 3 x 1 KB (16 B x
// 64 lanes). Tail: 64 B via 4 B x 16 lanes (exec-masked; inactive lanes write
// nothing). vmcnt bookkeeping: always 4 ops per row.
__device__ __forceinline__ void dma_row(const float* grow, float* lbuf, int lane)
{
    const char* g16 = (const char*)grow + lane * 16;
    const char* g4  = (const char*)grow + 3072 + lane * 4;
    char* l = (char*)lbuf;
    __builtin_amdgcn_global_load_lds((const __attribute__((address_space(1))) void*)(g16),
                                     (__attribute__((address_space(3))) void*)(l), 16, 0, 0);
    __builtin_amdgcn_global_load_lds((const __attribute__((address_space(1))) void*)(g16 + 1024),
                                     (__attribute__((address_space(3))) void*)(l + 1024), 16, 0, 0);
    __builtin_amdgcn_global_load_lds((const __attribute__((address_space(1))) void*)(g16 + 2048),
                                     (__attribute__((address_space(3))) void*)(l + 2048), 16, 0, 0);
    if (lane < 16)
        __builtin_amdgcn_global_load_lds((const __attribute__((address_space(1))) void*)(g4),
                                         (__attribute__((address_space(3))) void*)(l + 3072), 4, 0, 0);
}

// ================= E-form chain step (fp16 MFMA, fp32 passthrough) =========
// acc <- mat^T * acc  computed as  acc += (mat - I)^T_f16 * f16(acc).
// Same k-slot bijection as the verified stepT: slot t=0..3 <-> k=16*0+4q+t,
// slot t=4..7 <-> k=16*1+4q+t, identical on A and B; logical k=28..31 zeroed
// on the A side (q3 upper block). B comes from acc fully IN-LANE (D-frag row
// map == B-frag k map, R3/R5-verified). C operand = acc (fp32, exact): the
// running product is NEVER quantized — f16 error enters only scaled by
// ||E||~0.03, so per-step error ~3e-4 and 4 MFMAs replace 16.
// dia[t] = 1 exactly when this lane's (c,q) hits the diagonal m==k at slot t.
template<int STRIDE>
__device__ __forceinline__ void stepE(const float* a0, const float* a1,
                                      float4v acc[2][2], bool q3,
                                      const float dia[4])
{
    float av[2][2][4];
#pragma unroll
    for (int t = 0; t < 4; ++t)
#pragma unroll
        for (int Ro = 0; Ro < 2; ++Ro) {
            av[Ro][0][t] = a0[t * STRIDE + 16 * Ro];
            av[Ro][1][t] = a1[t * STRIDE + 16 * Ro];
        }
    // E = M - I on the two (Ro==KB) diagonal blocks
#pragma unroll
    for (int t = 0; t < 4; ++t) {
        av[0][0][t] -= dia[t];
        av[1][1][t] -= dia[t];
    }
    // logical k=28..31 -> 0 (A-side pad containment, after dia)
#pragma unroll
    for (int Ro = 0; Ro < 2; ++Ro)
#pragma unroll
        for (int t = 0; t < 4; ++t)
            av[Ro][1][t] = q3 ? 0.f : av[Ro][1][t];

    half8 Av[2];
#pragma unroll
    for (int Ro = 0; Ro < 2; ++Ro)
#pragma unroll
        for (int t = 0; t < 4; ++t) {
            Av[Ro][t]     = (_Float16)av[Ro][0][t];
            Av[Ro][4 + t] = (_Float16)av[Ro][1][t];
        }

    half8 Bv[2];
#pragma unroll
    for (int Co = 0; Co < 2; ++Co)
#pragma unroll
        for (int t = 0; t < 4; ++t) {
            Bv[Co][t]     = (_Float16)acc[0][Co][t];
            Bv[Co][4 + t] = (_Float16)acc[1][Co][t];
        }

#pragma unroll
    for (int Ro = 0; Ro < 2; ++Ro)
#pragma unroll
        for (int Co = 0; Co < 2; ++Co)
            acc[Ro][Co] = __builtin_amdgcn_mfma_f32_16x16x32_f16(
                Av[Ro], Bv[Co], acc[Ro][Co], 0, 0, 0);
}

// ================= two-term bf16 step (verified) — merge/combine only ======
template<int STRIDE>
__device__ __forceinline__ void stepT(const float* a0, const float* a1,
                                      float4v acc[2][2], bool q3)
{
    float av[2][2][4];
#pragma unroll
    for (int t = 0; t < 4; ++t)
#pragma unroll
        for (int Ro = 0; Ro < 2; ++Ro) {
            av[Ro][0][t] = a0[t * STRIDE + 16 * Ro];
            av[Ro][1][t] = a1[t * STRIDE + 16 * Ro];
        }
#pragma unroll
    for (int Ro = 0; Ro < 2; ++Ro)
#pragma unroll
        for (int t = 0; t < 4; ++t)
            av[Ro][1][t] = q3 ? 0.f : av[Ro][1][t];

    FragU Af[2][2];
#pragma unroll
    for (int Ro = 0; Ro < 2; ++Ro)
#pragma unroll
        for (int KB = 0; KB < 2; ++KB) {
            HL4 h = hilo4(av[Ro][KB][0], av[Ro][KB][1], av[Ro][KB][2], av[Ro][KB][3]);
            Af[Ro][KB].u[0] = h.h01; Af[Ro][KB].u[1] = h.h23;
            Af[Ro][KB].u[2] = h.l01; Af[Ro][KB].u[3] = h.l23;
        }

    FragU Bd[2][2], B2[2][2];
#pragma unroll
    for (int KB = 0; KB < 2; ++KB)
#pragma unroll
        for (int Co = 0; Co < 2; ++Co) {
            HL4 h = hilo4(acc[KB][Co][0], acc[KB][Co][1], acc[KB][Co][2], acc[KB][Co][3]);
            Bd[KB][Co].u[0] = h.h01; Bd[KB][Co].u[1] = h.h23;
            Bd[KB][Co].u[2] = h.h01; Bd[KB][Co].u[3] = h.h23;
            B2[KB][Co].u[0] = h.l01; B2[KB][Co].u[1] = h.l23;
            B2[KB][Co].u[2] = 0u;    B2[KB][Co].u[3] = 0u;
        }

#pragma unroll
    for (int Ro = 0; Ro < 2; ++Ro)
#pragma unroll
        for (int Co = 0; Co < 2; ++Co) {
            float4v d = {0.f, 0.f, 0.f, 0.f};
#pragma unroll
            for (int KB = 0; KB < 2; ++KB) {
                d = __builtin_amdgcn_mfma_f32_16x16x32_bf16(Af[Ro][KB].v, Bd[KB][Co].v, d, 0, 0, 0);
                d = __builtin_amdgcn_mfma_f32_16x16x32_bf16(Af[Ro][KB].v, B2[KB][Co].v, d, 0, 0, 0);
            }
            acc[Ro][Co] = d;
        }
}

// ================= fused kernel: one block per sentence =================
// 4 waves; wave w runs TWO interleaved 8-word chains (a=words 0..7, b=8..15),
// sub-step order a0,b0,a1,b1,... Chain steps use the f16-E passthrough step
// (4 MFMAs); merge + block-combine use the verified bf16 stepT. DMA: rows
// rotate through 3 buffers (row s -> buf s%3), depth-2 prefetch, in-loop
// vmcnt(8); tail sub-steps issue nothing and wait vmcnt(4)/vmcnt(0) (no dup
// re-issues). LDS: 4 x 3 x 3328 B = 39936 B -> 4 blocks/CU, grid resident.
__global__ __launch_bounds__(NW * 64, 4) void w2m_fusedE(
    const int* __restrict__ sent,
    const float* __restrict__ table,
    float* __restrict__ out)
{
    __shared__ float SH[NW * 3 * BUFF] __attribute__((aligned(16)));
    const int lane = threadIdx.x & 63;
    const int wid  = threadIdx.x >> 6;   // 0..3
    const int b = blockIdx.x;
    const int c = lane & 15;
    const int quad = lane >> 4;
    const bool q3 = (quad == 3);
    const int qc = q3 ? 2 : quad;        // clamp so chain a1 reads stay <832

    // dia[t] = 1 iff m==k at slot t for this lane: c>>2==quad and c&3==t
    float dia[4];
#pragma unroll
    for (int t = 0; t < 4; ++t)
        dia[t] = ((c >> 2) == quad && (c & 3) == t) ? 1.f : 0.f;

    float* B0  = &SH[wid * 3 * BUFF];
    float* B1  = B0 + BUFF;
    float* B2b = B0 + 2 * BUFF;

    const int myidx = sent[b * SEQ + CH * wid + (lane & 15)];
    // row sequence s: a0,b0,a1,b1,... -> local word (s&1)*8 + (s>>1)
    int jr[16];
#pragma unroll
    for (int s = 0; s < 16; ++s)
        jr[s] = __builtin_amdgcn_readlane(myidx, (s & 1) * 8 + (s >> 1));

    // ---- prologue: rows 0,1,2 in flight (bufs 0,1,2)
    dma_row(table + (size_t)jr[0] * EMB, B0, lane);
    dma_row(table + (size_t)jr[1] * EMB, B1, lane);
    dma_row(table + (size_t)jr[2] * EMB, B2b, lane);
    __builtin_amdgcn_s_waitcnt(0x0078);  // vmcnt(8): row0 landed

    // init accA = (word a0)^T (transposed b128 read; pad-col junk masked at
    // store; pad rows get A-side zeros every step).
    float4v accA[2][2], accB[2][2];
#pragma unroll
    for (int R = 0; R < 2; ++R)
#pragma unroll
        for (int Cc = 0; Cc < 2; ++Cc) {
            int rcl = 16 * Cc + c; if (rcl > 27) rcl = 27;
            accA[R][Cc] = *(const float4v*)&B0[rcl * D + 16 * R + 4 * quad];
        }

    // per-lane, per-buffer A bases (all step offsets become immediates)
    const float* a00 = B0  + 4 * quad * D + c;
    const float* a10 = B0  + (16 + 4 * qc) * D + c;
    const float* a01 = B1  + 4 * quad * D + c;
    const float* a11 = B1  + (16 + 4 * qc) * D + c;
    const float* a02 = B2b + 4 * quad * D + c;
    const float* a12 = B2b + (16 + 4 * qc) * D + c;

    // ---- interleaved chains, fully unrolled. Sub-step s:
    //   s<=13: lgkmcnt(0) (prior reads of buf (s+2)%3 done) -> issue row s+2
    //          -> vmcnt(8): row s landed, s+1/s+2 in flight.
    //   s==14: no issue, vmcnt(4) (row 14 landed, row 15 in flight).
    //   s==15: no issue, vmcnt(0).
    // s==1 inits accB; s>=2 steps (even -> accA, odd -> accB).
    // NOTE: s_waitcnt argument must be a literal in EACH call (front-end
    // ICE check happens before unrolling) — hence the branch ladder.
#pragma unroll
    for (int s = 1; s < 16; ++s) {
        if (s <= 13) {
            __builtin_amdgcn_s_waitcnt(0xC07F);  // lgkmcnt(0)
            const int tb = (s + 2) % 3;
            float* nB = (tb == 0) ? B0 : (tb == 1) ? B1 : B2b;
            dma_row(table + (size_t)jr[s + 2] * EMB, nB, lane);
        }
        __builtin_amdgcn_sched_barrier(0);
        if (s <= 13)      __builtin_amdgcn_s_waitcnt(0x0078);  // vmcnt(8) lgkm(0)
        else if (s == 14) __builtin_amdgcn_s_waitcnt(0x0074);  // vmcnt(4) lgkm(0)
        else              __builtin_amdgcn_s_waitcnt(0x0070);  // vmcnt(0) lgkm(0)
        __builtin_amdgcn_sched_barrier(0);

        if (s == 1) {
            // init accB = (word b0)^T from buf1
#pragma unroll
            for (int R = 0; R < 2; ++R)
#pragma unroll
                for (int Cc = 0; Cc < 2; ++Cc) {
                    int rcl = 16 * Cc + c; if (rcl > 27) rcl = 27;
                    accB[R][Cc] = *(const float4v*)&B1[rcl * D + 16 * R + 4 * quad];
                }
        } else {
            float4v (*acc)[2] = (s & 1) ? accB : accA;
            const int cb = s % 3;
            if (cb == 0)      stepE<D>(a00, a10, acc, q3, dia);
            else if (cb == 1) stepE<D>(a01, a11, acc, q3, dia);
            else              stepE<D>(a02, a12, acc, q3, dia);
        }
    }

    // ---- merge: T_w = T_b * T_a (verified bf16 stepT). Publish P_b = T_b^T
    // into own scratch (transposed write), then acc <- (P_b)^T * accA.
    __builtin_amdgcn_sched_barrier(0);
    float* SCR = B0;  // region 3*832 = 2496 floats; max idx used 1147
#pragma unroll
    for (int KB = 0; KB < 2; ++KB)
#pragma unroll
        for (int Co = 0; Co < 2; ++Co)
#pragma unroll
            for (int i = 0; i < 4; ++i)
                SCR[(16 * Co + c) * SCRW + 16 * KB + 4 * quad + i] = accB[KB][Co][i];
    __builtin_amdgcn_sched_barrier(0);
    __builtin_amdgcn_s_waitcnt(0xC07F);  // lgkmcnt(0): publish visible
    __builtin_amdgcn_sched_barrier(0);
    stepT<SCRW>(SCR + 4 * quad * SCRW + c,
                SCR + (16 + 4 * quad) * SCRW + c, accA, q3);

    // ---- publish T_w row-major (WAR on SCR: drain stepT's reads first)
    __builtin_amdgcn_s_waitcnt(0xC07F);  // lgkmcnt(0)
    __builtin_amdgcn_sched_barrier(0);
#pragma unroll
    for (int R = 0; R < 2; ++R)
#pragma unroll
        for (int Cc = 0; Cc < 2; ++Cc)
#pragma unroll
            for (int i = 0; i < 4; ++i)
                SCR[(16 * R + 4 * quad + i) * SCRW + 16 * Cc + c] = accA[R][Cc][i];
    __syncthreads();

    // ---- combine (redundant on all waves): X = P3, then X = Pj*X, j=2,1,0.
    const float* S3 = &SH[3 * 3 * BUFF];
#pragma unroll
    for (int R = 0; R < 2; ++R)
#pragma unroll
        for (int Cc = 0; Cc < 2; ++Cc)
            accA[R][Cc] = *(const float4v*)&S3[(16 * Cc + c) * SCRW + 16 * R + 4 * quad];

#pragma unroll
    for (int j = 2; j >= 0; --j) {
        const float* reg = &SH[j * 3 * BUFF];
        stepT<SCRW>(reg + 4 * quad * SCRW + c,
                    reg + (16 + 4 * quad) * SCRW + c, accA, q3);
    }

    // ---- store rows/cols < 28
    if (wid == 0) {
        float* orow = out + (size_t)b * EMB;
#pragma unroll
        for (int R = 0; R < 2; ++R)
#pragma unroll
            for (int Cc = 0; Cc < 2; ++Cc)
#pragma unroll
                for (int i = 0; i < 4; ++i) {
                    const int row = 16 * R + 4 * quad + i;
                    const int col = 16 * Cc + c;
                    if (row < D && col < D) orow[row * D + col] = accA[R][Cc][i];
                }
    }
}

extern "C" void kernel_launch(void* const* d_in, const int* in_sizes, int n_in,
                              void* d_out, int out_size, void* d_ws, size_t ws_size,
                              hipStream_t stream) {
    const int* sent = (const int*)d_in[0];
    const float* table = (const float*)d_in[1];
    float* out = (float*)d_out;
    const int batch = in_sizes[0] / SEQ;                  // 1024
    (void)d_ws; (void)ws_size;                            // workspace unused

    hipLaunchKernelGGL(w2m_fusedE, dim3(batch), dim3(NW * 64), 0, stream,
                       sent, table, out);
}

// Round 9
// 148.131 us; speedup vs baseline: 1.0396x; 1.0082x over previous
//
#include <hip/hip_runtime.h>
#include <stdint.h>

#define SEQ 64
#define D 28
#define EMB 784   // 28*28
#define NW 8      // waves per block (one block = one sentence)
#define CH 8      // words per wave: single 8-word chain
#define BUFF 832  // B-buffer floats: 3328 B DMA region (3*1024 + tail)
#define SCRW 36   // scratch row stride (floats); 2-way-free banks

typedef float float4v __attribute__((ext_vector_type(4)));
typedef _Float16 half8 __attribute__((ext_vector_type(8)));

__device__ __forceinline__ unsigned fbits(float x) { union { float f; unsigned u; } t; t.f = x; return t.u; }
__device__ __forceinline__ float fof(unsigned u) { union { unsigned u; float f; } t; t.u = u; return t.f; }

// ---- async global->LDS DMA of one 3136 B row. Main loads: 3 x 1 KB (16 B x
// 64 lanes). Tail: 64 B via 4 B x 16 lanes (exec-masked; inactive lanes write
// nothing). vmcnt bookkeeping: always 4 ops per row. Verbatim from R8-passing.
__device__ __forceinline__ void dma_row(const float* grow, float* lbuf, int lane)
{
    const char* g16 = (const char*)grow + lane * 16;
    const char* g4  = (const char*)grow + 3072 + lane * 4;
    char* l = (char*)lbuf;
    __builtin_amdgcn_global_load_lds((const __attribute__((address_space(1))) void*)(g16),
                                     (__attribute__((address_space(3))) void*)(l), 16, 0, 0);
    __builtin_amdgcn_global_load_lds((const __attribute__((address_space(1))) void*)(g16 + 1024),
                                     (__attribute__((address_space(3))) void*)(l + 1024), 16, 0, 0);
    __builtin_amdgcn_global_load_lds((const __attribute__((address_space(1))) void*)(g16 + 2048),
                                     (__attribute__((address_space(3))) void*)(l + 2048), 16, 0, 0);
    if (lane < 16)
        __builtin_amdgcn_global_load_lds((const __attribute__((address_space(1))) void*)(g4),
                                         (__attribute__((address_space(3))) void*)(l + 3072), 4, 0, 0);
}

// ================= E-form step (fp16 MFMA, fp32 passthrough) ===============
// acc <- mat^T-ish * acc computed as acc += (A - I)_f16 * f16(acc), where
// A[m][k] = mat[k*STRIDE + m]. fp32 accumulator is NEVER quantized; f16
// error enters scaled by ||A - I|| (~0.03 for table rows, ~0.3 for partial
// products) -> per-step error <= ~2e-4. k-slot map identical on A and B
// (slot t<4 <-> k=4q+t, slot t>=4 <-> k=16+4q+t); logical k=28..31 zeroed on
// the A side (q3 upper block). B comes from acc fully IN-LANE (D-frag row
// map == B-frag k map, R3/R5/R8-verified). Verbatim from R8-passing stepE.
// dia[t] = 1 exactly when this lane's (c,q) hits the diagonal m==k at slot t.
template<int STRIDE>
__device__ __forceinline__ void stepE(const float* a0, const float* a1,
                                      float4v acc[2][2], bool q3,
                                      const float dia[4])
{
    float av[2][2][4];
#pragma unroll
    for (int t = 0; t < 4; ++t)
#pragma unroll
        for (int Ro = 0; Ro < 2; ++Ro) {
            av[Ro][0][t] = a0[t * STRIDE + 16 * Ro];
            av[Ro][1][t] = a1[t * STRIDE + 16 * Ro];
        }
    // E = M - I on the two (Ro==KB) diagonal blocks
#pragma unroll
    for (int t = 0; t < 4; ++t) {
        av[0][0][t] -= dia[t];
        av[1][1][t] -= dia[t];
    }
    // logical k=28..31 -> 0 (A-side pad containment, after dia)
#pragma unroll
    for (int Ro = 0; Ro < 2; ++Ro)
#pragma unroll
        for (int t = 0; t < 4; ++t)
            av[Ro][1][t] = q3 ? 0.f : av[Ro][1][t];

    half8 Av[2];
#pragma unroll
    for (int Ro = 0; Ro < 2; ++Ro)
#pragma unroll
        for (int t = 0; t < 4; ++t) {
            Av[Ro][t]     = (_Float16)av[Ro][0][t];
            Av[Ro][4 + t] = (_Float16)av[Ro][1][t];
        }

    half8 Bv[2];
#pragma unroll
    for (int Co = 0; Co < 2; ++Co)
#pragma unroll
        for (int t = 0; t < 4; ++t) {
            Bv[Co][t]     = (_Float16)acc[0][Co][t];
            Bv[Co][4 + t] = (_Float16)acc[1][Co][t];
        }

#pragma unroll
    for (int Ro = 0; Ro < 2; ++Ro)
#pragma unroll
        for (int Co = 0; Co < 2; ++Co)
            acc[Ro][Co] = __builtin_amdgcn_mfma_f32_16x16x32_f16(
                Av[Ro], Bv[Co], acc[Ro][Co], 0, 0, 0);
}

// ================= fused kernel: one block per sentence, 8 waves ===========
// Wave w computes T_w = (prod of words 8w..8w+7)^T via a single 8-row chain
// (init + 7 stepE; DMA rows rotate through 3 buffers, row s -> buf s%3,
// depth-2 prefetch, in-loop vmcnt(8), tail vmcnt(4)/vmcnt(0)). Waves publish
// T_w to their LDS region; after one barrier all waves redundantly combine
// X = P0*...*P7 (init from T7 + 7 stepE with ||P-I||~0.3) and wave 0 stores.
// Rationale: per-wave serial DMA-wait chain HALVES vs NW=4/CH=16 (10 vs 18
// dependent waits) while doubling wave-level concurrency — attacks the
// measured ~6900-cy-per-wait queueing latency with idle HBM headroom.
// LDS: 8 waves x 3 x 3328 B = 79872 B -> 2 blocks/CU = 16 waves/CU (same
// residency as R8). VGPR ~64 -> no occupancy pressure.
__global__ __launch_bounds__(NW * 64, 4) void w2m_fused8(
    const int* __restrict__ sent,
    const float* __restrict__ table,
    float* __restrict__ out)
{
    __shared__ float SH[NW * 3 * BUFF] __attribute__((aligned(16)));
    const int lane = threadIdx.x & 63;
    const int wid  = threadIdx.x >> 6;   // 0..7
    const int b = blockIdx.x;
    const int c = lane & 15;
    const int quad = lane >> 4;
    const bool q3 = (quad == 3);
    const int qc = q3 ? 2 : quad;        // clamp so chain a1 reads stay <832

    // dia[t] = 1 iff m==k at slot t for this lane: c>>2==quad and c&3==t
    float dia[4];
#pragma unroll
    for (int t = 0; t < 4; ++t)
        dia[t] = ((c >> 2) == quad && (c & 3) == t) ? 1.f : 0.f;

    float* B0  = &SH[wid * 3 * BUFF];
    float* B1  = B0 + BUFF;
    float* B2b = B0 + 2 * BUFF;

    const int myidx = sent[b * SEQ + CH * wid + (lane & 7)];
    int jr[CH];
#pragma unroll
    for (int s = 0; s < CH; ++s) jr[s] = __builtin_amdgcn_readlane(myidx, s);

    // ---- prologue: rows 0,1,2 in flight (bufs 0,1,2)
    dma_row(table + (size_t)jr[0] * EMB, B0, lane);
    dma_row(table + (size_t)jr[1] * EMB, B1, lane);
    dma_row(table + (size_t)jr[2] * EMB, B2b, lane);
    __builtin_amdgcn_s_waitcnt(0x0078);  // vmcnt(8): row0 landed

    // init acc = (word 0)^T (transposed b128 read; pad-col junk masked at
    // store; pad rows get A-side zeros every step).
    float4v acc[2][2];
#pragma unroll
    for (int R = 0; R < 2; ++R)
#pragma unroll
        for (int Cc = 0; Cc < 2; ++Cc) {
            int rcl = 16 * Cc + c; if (rcl > 27) rcl = 27;
            acc[R][Cc] = *(const float4v*)&B0[rcl * D + 16 * R + 4 * quad];
        }

    // per-lane, per-buffer A bases (all step offsets become immediates)
    const float* a00 = B0  + 4 * quad * D + c;
    const float* a10 = B0  + (16 + 4 * qc) * D + c;
    const float* a01 = B1  + 4 * quad * D + c;
    const float* a11 = B1  + (16 + 4 * qc) * D + c;
    const float* a02 = B2b + 4 * quad * D + c;
    const float* a12 = B2b + (16 + 4 * qc) * D + c;

    // ---- chain, fully unrolled. Sub-step s:
    //   s<=5: lgkmcnt(0) (prior reads of buf (s+2)%3 done) -> issue row s+2
    //         -> vmcnt(8): row s landed, s+1/s+2 in flight.
    //   s==6: no issue, vmcnt(4) (row 6 landed, row 7 in flight).
    //   s==7: no issue, vmcnt(0).
    // NOTE: s_waitcnt arg must be a literal in EACH call (front-end check
    // precedes unrolling) — hence the branch ladder on constant-folded s.
#pragma unroll
    for (int s = 1; s < CH; ++s) {
        if (s <= 5) {
            __builtin_amdgcn_s_waitcnt(0xC07F);  // lgkmcnt(0)
            const int tb = (s + 2) % 3;
            float* nB = (tb == 0) ? B0 : (tb == 1) ? B1 : B2b;
            dma_row(table + (size_t)jr[s + 2] * EMB, nB, lane);
        }
        __builtin_amdgcn_sched_barrier(0);
        if (s <= 5)      __builtin_amdgcn_s_waitcnt(0x0078);  // vmcnt(8) lgkm(0)
        else if (s == 6) __builtin_amdgcn_s_waitcnt(0x0074);  // vmcnt(4) lgkm(0)
        else             __builtin_amdgcn_s_waitcnt(0x0070);  // vmcnt(0) lgkm(0)
        __builtin_amdgcn_sched_barrier(0);

        const int cb = s % 3;
        if (cb == 0)      stepE<D>(a00, a10, acc, q3, dia);
        else if (cb == 1) stepE<D>(a01, a11, acc, q3, dia);
        else              stepE<D>(a02, a12, acc, q3, dia);
    }

    // ---- publish T_w row-major (stride 36) into own region (overwrites own
    // B-bufs; max idx 1147 < 2496; WAR vs step-7 ds_reads compiler-ordered).
    __builtin_amdgcn_sched_barrier(0);
    float* SCR = B0;
#pragma unroll
    for (int R = 0; R < 2; ++R)
#pragma unroll
        for (int Cc = 0; Cc < 2; ++Cc)
#pragma unroll
            for (int i = 0; i < 4; ++i)
                SCR[(16 * R + 4 * quad + i) * SCRW + 16 * Cc + c] = acc[R][Cc][i];
    __syncthreads();  // drains own vmcnt/lgkmcnt per wave; all T_w stable

    // ---- combine (redundant on all waves): X = P7, then X = Pj*X, j=6..0.
    // Init acc = P7 via transposed read of T7 (same pattern as R8's S3 init).
    const float* S7 = &SH[7 * 3 * BUFF];
#pragma unroll
    for (int R = 0; R < 2; ++R)
#pragma unroll
        for (int Cc = 0; Cc < 2; ++Cc)
            acc[R][Cc] = *(const float4v*)&S7[(16 * Cc + c) * SCRW + 16 * R + 4 * quad];

    // 7 combine steps, stepE with mat = published T_j (A[m][k] = T_j[k][m]
    // = P_j[m][k] -> acc <- P_j*acc). Unclamped a1 max offset 1147 < 2496;
    // junk pad rows/cols stay in pads (A-side q3 zeros + store mask).
#pragma unroll
    for (int j = 6; j >= 0; --j) {
        const float* reg = &SH[j * 3 * BUFF];
        stepE<SCRW>(reg + 4 * quad * SCRW + c,
                    reg + (16 + 4 * quad) * SCRW + c, acc, q3, dia);
    }

    // ---- store rows/cols < 28
    if (wid == 0) {
        float* orow = out + (size_t)b * EMB;
#pragma unroll
        for (int R = 0; R < 2; ++R)
#pragma unroll
            for (int Cc = 0; Cc < 2; ++Cc)
#pragma unroll
                for (int i = 0; i < 4; ++i) {
                    const int row = 16 * R + 4 * quad + i;
                    const int col = 16 * Cc + c;
                    if (row < D && col < D) orow[row * D + col] = acc[R][Cc][i];
                }
    }
}

extern "C" void kernel_launch(void* const* d_in, const int* in_sizes, int n_in,
                              void* d_out, int out_size, void* d_ws, size_t ws_size,
                              hipStream_t stream) {
    const int* sent = (const int*)d_in[0];
    const float* table = (const float*)d_in[1];
    float* out = (float*)d_out;
    const int batch = in_sizes[0] / SEQ;                  // 1024
    (void)d_ws; (void)ws_size;                            // workspace unused

    hipLaunchKernelGGL(w2m_fused8, dim3(batch), dim3(NW * 64), 0, stream,
                       sent, table, out);
}